// Round 1
// baseline (118.980 us; speedup 1.0000x reference)
//
#include <hip/hip_runtime.h>

// BoundaryLoss: mean(sigmoid(logits) * EDT2D(target))
// B=8, C=1, H=256, W=256 (fixed by the reference setup_inputs()).
//
// Pass 1 (row_dist): exact 1D distance along W to nearest target>0, squared.
// Pass 2 (col_pass): d2(i,w) = min_j dr2(j,w) + (i-j)^2  (exact separable EDT),
//                    fused with sqrt + sigmoid(logit) + per-column reduction.
// Pass 3 (final_reduce): sum 2048 column partials -> mean -> d_out[0].

#define BIGF 1000000.0f

constexpr int B = 8;
constexpr int H = 256;
constexpr int W = 256;
constexpr int NPIX = B * H * W;   // 524288

__device__ __forceinline__ float block_reduce_sum_256(float v) {
    // 256 threads = 4 waves of 64
    #pragma unroll
    for (int off = 32; off > 0; off >>= 1)
        v += __shfl_down(v, off, 64);
    __shared__ float s[4];
    const int lane = threadIdx.x & 63;
    const int wid  = threadIdx.x >> 6;
    if (lane == 0) s[wid] = v;
    __syncthreads();
    if (wid == 0) {
        v = (lane < 4) ? s[lane] : 0.0f;
        v += __shfl_down(v, 2, 64);
        v += __shfl_down(v, 1, 64);
    }
    return v;  // valid on thread 0
}

// One block per (b*H + h) row; 256 threads = one per w.
__global__ __launch_bounds__(W) void row_dist_kernel(
        const int* __restrict__ target, float* __restrict__ dr2) {
    const int row = blockIdx.x;       // b*H + h  (C=1 so flat layout matches)
    const int w   = threadIdx.x;      // 0..255

    __shared__ int s_mask[W];
    const int t = target[row * W + w];
    // fg -> 0 ; background -> large OR-mask so candidate >= 65536
    s_mask[w] = (t > 0) ? 0 : (1 << 16);
    __syncthreads();

    int d = 1 << 20;
    #pragma unroll 8
    for (int j = 0; j < W; ++j) {
        const int cand = abs(w - j) | s_mask[j];   // LDS broadcast, branchless
        d = min(d, cand);
    }
    const float df = (d < (1 << 16)) ? (float)d : BIGF;
    dr2[row * W + w] = df * df;
}

// One block per (b*W + w) column; 256 threads = one per output row i.
__global__ __launch_bounds__(H) void col_pass_kernel(
        const float* __restrict__ logits, const float* __restrict__ dr2,
        float* __restrict__ partials) {
    const int bw = blockIdx.x;
    const int b  = bw >> 8;           // / W
    const int w  = bw & (W - 1);      // % W
    const int i  = threadIdx.x;       // 0..255

    __shared__ float s_dr2[H];
    s_dr2[i] = dr2[(b * H + i) * W + w];
    __syncthreads();

    float best = 3.0e12f;             // > BIG^2 + H^2
    const float fi = (float)i;
    #pragma unroll 8
    for (int j = 0; j < H; ++j) {
        const float t = fi - (float)j;
        best = fminf(best, fmaf(t, t, s_dr2[j]));  // LDS broadcast per j
    }
    const float dist = sqrtf(best);

    const float x    = logits[(b * H + i) * W + w];
    const float prob = 1.0f / (1.0f + expf(-x));

    const float v   = block_reduce_sum_256(prob * dist);
    if (threadIdx.x == 0) partials[bw] = v;
}

__global__ __launch_bounds__(256) void final_reduce_kernel(
        const float* __restrict__ partials, float* __restrict__ out,
        int n, float scale) {
    float v = 0.0f;
    for (int idx = threadIdx.x; idx < n; idx += 256)
        v += partials[idx];
    v = block_reduce_sum_256(v);
    if (threadIdx.x == 0) out[0] = v * scale;
}

extern "C" void kernel_launch(void* const* d_in, const int* in_sizes, int n_in,
                              void* d_out, int out_size, void* d_ws, size_t ws_size,
                              hipStream_t stream) {
    const float* logits = (const float*)d_in[0];
    const int*   target = (const int*)d_in[1];

    float* dr2      = (float*)d_ws;           // NPIX floats (2 MB)
    float* partials = dr2 + NPIX;             // B*W floats (8 KB)

    row_dist_kernel<<<B * H, W, 0, stream>>>(target, dr2);
    col_pass_kernel<<<B * W, H, 0, stream>>>(logits, dr2, partials);
    final_reduce_kernel<<<1, 256, 0, stream>>>(partials, (float*)d_out,
                                               B * W, 1.0f / (float)NPIX);
}

// Round 2
// 74.562 us; speedup vs baseline: 1.5957x; 1.5957x over previous
//
#include <hip/hip_runtime.h>

// BoundaryLoss: mean(sigmoid(logits) * EDT2D(target)), B=8, H=W=256.
//
// Separable EDT with strength-reduced inner loop:
//   min_j (x-j)^2 + m_j  =  x^2 + min_j (j^2 + m_j - 2xj)
// q_j = j^2 + m_j staged in LDS; inner step = 1 fma + min per candidate.
// One wave per row/column; each lane produces 4 outputs (lane + 64m) so each
// ds_read_b128 (broadcast, conflict-free) feeds 16 fma+min ops.
// All candidate values are exact integers < 2^24 in fp32 -> bit-exact vs ref.

#define BIGF 1000000.0f
#define BIG2 (BIGF * BIGF)   // fp32 rounding of 1e12, same as ref's BIG*BIG

constexpr int B = 8;
constexpr int H = 256;
constexpr int W = 256;
constexpr int NPIX = B * H * W;   // 524288

__device__ __forceinline__ float block_reduce_sum_256(float v) {
    #pragma unroll
    for (int off = 32; off > 0; off >>= 1)
        v += __shfl_down(v, off, 64);
    __shared__ float s[4];
    const int lane = threadIdx.x & 63;
    const int wid  = threadIdx.x >> 6;
    if (lane == 0) s[wid] = v;
    __syncthreads();
    if (wid == 0) {
        v = (lane < 4) ? s[lane] : 0.0f;
        v += __shfl_down(v, 2, 64);
        v += __shfl_down(v, 1, 64);
    }
    return v;  // valid on thread 0
}

// 16 candidates (4 outputs x 4 j's) per LDS float4.
__device__ __forceinline__ void upd16(const float4 m, float j0,
                                      float n0, float n1, float n2, float n3,
                                      float& b0, float& b1, float& b2, float& b3) {
    const float j1 = j0 + 1.0f, j2 = j0 + 2.0f, j3 = j0 + 3.0f;
    {
        const float c0 = fmaf(n0, j0, m.x), c1 = fmaf(n0, j1, m.y);
        const float c2 = fmaf(n0, j2, m.z), c3 = fmaf(n0, j3, m.w);
        b0 = fminf(b0, fminf(fminf(c0, c1), fminf(c2, c3)));
    }
    {
        const float c0 = fmaf(n1, j0, m.x), c1 = fmaf(n1, j1, m.y);
        const float c2 = fmaf(n1, j2, m.z), c3 = fmaf(n1, j3, m.w);
        b1 = fminf(b1, fminf(fminf(c0, c1), fminf(c2, c3)));
    }
    {
        const float c0 = fmaf(n2, j0, m.x), c1 = fmaf(n2, j1, m.y);
        const float c2 = fmaf(n2, j2, m.z), c3 = fmaf(n2, j3, m.w);
        b2 = fminf(b2, fminf(fminf(c0, c1), fminf(c2, c3)));
    }
    {
        const float c0 = fmaf(n3, j0, m.x), c1 = fmaf(n3, j1, m.y);
        const float c2 = fmaf(n3, j2, m.z), c3 = fmaf(n3, j3, m.w);
        b3 = fminf(b3, fminf(fminf(c0, c1), fminf(c2, c3)));
    }
}

// Pass 1: row squared-distances. 512 blocks x 256 thr; wave r -> row blk*4+r.
__global__ __launch_bounds__(256) void row_dist_kernel(
        const int* __restrict__ target, float* __restrict__ dr2) {
    __shared__ float s_q[4][256];
    const int lane = threadIdx.x & 63;
    const int wv   = threadIdx.x >> 6;
    const int row  = (blockIdx.x << 2) + wv;

    // q_j = j^2 + (fg ? 0 : BIG2), j = 4*lane..4*lane+3 (coalesced int4 load)
    const int4 tv = *(const int4*)(target + row * W + (lane << 2));
    const float fj0 = (float)(lane << 2);
    const float fj1 = fj0 + 1.0f, fj2 = fj0 + 2.0f, fj3 = fj0 + 3.0f;
    float4 q;
    q.x = fmaf(fj0, fj0, tv.x > 0 ? 0.0f : BIG2);
    q.y = fmaf(fj1, fj1, tv.y > 0 ? 0.0f : BIG2);
    q.z = fmaf(fj2, fj2, tv.z > 0 ? 0.0f : BIG2);
    q.w = fmaf(fj3, fj3, tv.w > 0 ? 0.0f : BIG2);
    *(float4*)&s_q[wv][lane << 2] = q;
    __syncthreads();

    const float w0f = (float)lane,         w1f = (float)(lane + 64);
    const float w2f = (float)(lane + 128), w3f = (float)(lane + 192);
    const float n0 = -2.0f * w0f, n1 = -2.0f * w1f;
    const float n2 = -2.0f * w2f, n3 = -2.0f * w3f;
    float b0 = 4e12f, b1 = 4e12f, b2 = 4e12f, b3 = 4e12f;

    float fj = 0.0f;
    #pragma unroll 4
    for (int jv = 0; jv < 64; ++jv, fj += 4.0f) {
        const float4 m = *(const float4*)&s_q[wv][jv << 2];
        upd16(m, fj, n0, n1, n2, n3, b0, b1, b2, b3);
    }

    const int base = row * W + lane;      // coalesced stores
    dr2[base]       = fmaf(w0f, w0f, b0);
    dr2[base + 64]  = fmaf(w1f, w1f, b1);
    dr2[base + 128] = fmaf(w2f, w2f, b2);
    dr2[base + 192] = fmaf(w3f, w3f, b3);
}

// Pass 2: column EDT + sqrt + sigmoid + per-block reduce.
// 512 blocks x 256 thr; block -> (batch b, columns w0..w0+3); wave c -> col.
__global__ __launch_bounds__(256) void col_pass_kernel(
        const float* __restrict__ logits, const float* __restrict__ dr2,
        float* __restrict__ partials) {
    __shared__ float s_q[4][256];
    const int t  = threadIdx.x;
    const int b  = blockIdx.x >> 6;
    const int w0 = (blockIdx.x & 63) << 2;

    // stage q_j = j^2 + dr2[j][w0+c]; thread t handles j = t (float4 per thread)
    const float4 v  = *(const float4*)(dr2 + (b * H + t) * W + w0);
    const float fj  = (float)t;
    const float fj2 = fj * fj;              // exact (< 2^24)
    s_q[0][t] = fj2 + v.x;
    s_q[1][t] = fj2 + v.y;
    s_q[2][t] = fj2 + v.z;
    s_q[3][t] = fj2 + v.w;
    __syncthreads();

    const int lane = t & 63;
    const int wv   = t >> 6;
    const float i0f = (float)lane,         i1f = (float)(lane + 64);
    const float i2f = (float)(lane + 128), i3f = (float)(lane + 192);
    const float n0 = -2.0f * i0f, n1 = -2.0f * i1f;
    const float n2 = -2.0f * i2f, n3 = -2.0f * i3f;
    float b0 = 4e12f, b1 = 4e12f, b2 = 4e12f, b3 = 4e12f;

    float fjv = 0.0f;
    #pragma unroll 4
    for (int jv = 0; jv < 64; ++jv, fjv += 4.0f) {
        const float4 m = *(const float4*)&s_q[wv][jv << 2];
        upd16(m, fjv, n0, n1, n2, n3, b0, b1, b2, b3);
    }

    const int wcol = w0 + wv;
    const int base = (b * H + lane) * W + wcol;
    float acc;
    {
        const float dist = sqrtf(fmaf(i0f, i0f, b0));
        const float x = logits[base];
        acc = dist / (1.0f + expf(-x));
    }
    {
        const float dist = sqrtf(fmaf(i1f, i1f, b1));
        const float x = logits[base + 64 * W];
        acc += dist / (1.0f + expf(-x));
    }
    {
        const float dist = sqrtf(fmaf(i2f, i2f, b2));
        const float x = logits[base + 128 * W];
        acc += dist / (1.0f + expf(-x));
    }
    {
        const float dist = sqrtf(fmaf(i3f, i3f, b3));
        const float x = logits[base + 192 * W];
        acc += dist / (1.0f + expf(-x));
    }

    const float s = block_reduce_sum_256(acc);
    if (t == 0) partials[blockIdx.x] = s;
}

__global__ __launch_bounds__(256) void final_reduce_kernel(
        const float* __restrict__ partials, float* __restrict__ out,
        int n, float scale) {
    float v = 0.0f;
    for (int idx = threadIdx.x; idx < n; idx += 256)
        v += partials[idx];
    v = block_reduce_sum_256(v);
    if (threadIdx.x == 0) out[0] = v * scale;
}

extern "C" void kernel_launch(void* const* d_in, const int* in_sizes, int n_in,
                              void* d_out, int out_size, void* d_ws, size_t ws_size,
                              hipStream_t stream) {
    const float* logits = (const float*)d_in[0];
    const int*   target = (const int*)d_in[1];

    float* dr2      = (float*)d_ws;     // NPIX floats (2 MB)
    float* partials = dr2 + NPIX;       // 512 floats

    row_dist_kernel<<<B * H / 4, 256, 0, stream>>>(target, dr2);
    col_pass_kernel<<<B * W / 4, 256, 0, stream>>>(logits, dr2, partials);
    final_reduce_kernel<<<1, 256, 0, stream>>>(partials, (float*)d_out,
                                               B * W / 4, 1.0f / (float)NPIX);
}